// Round 18
// baseline (486.873 us; speedup 1.0000x reference)
//
#include <hip/hip_runtime.h>
#include <math.h>

#define N_NODES 100000
#define N_EDGES 1600000
#define F_IN    64
#define H       32
#define C       2
#define G       500
#define BN_EPS  1e-5f

#define NPART        8        // dst partitions == XCD count
#define NODES_PER_P  12500    // 100000 / 8
#define EPB          2048     // edges scanned per block in k_scatter

// ---------------------------------------------------------------- zero utils
__global__ __launch_bounds__(256) void k_zero_i(int* __restrict__ p, int n) {
    int i = blockIdx.x * 256 + threadIdx.x;
    if (i < n) p[i] = 0;
}

// ---- fused: xform0 (blocks [0,nblk_x)) + histogram (rest). Independent work
// sharing one dispatch: hides xform0's serial time under hist's atomics.
__global__ __launch_bounds__(256) void k_histx(
    const int* __restrict__ ei, int* __restrict__ deg,
    const float* __restrict__ x, const float* __restrict__ W1,
    float* __restrict__ y, int nblk_x)
{
    __shared__ float Wt[F_IN * H];   // Wt[k*H+f] = W1[f*F_IN+k]
    __shared__ float xs[8 * F_IN];
    int tid = threadIdx.x;
    if ((int)blockIdx.x >= nblk_x) {
        // ---- histogram part
        int e = ((int)blockIdx.x - nblk_x) * 256 + tid;
        if (e < N_EDGES) atomicAdd(&deg[ei[N_EDGES + e]], 1);
        return;
    }
    // ---- xform0 part: y0 = x @ W1^T (8 nodes/block)
    for (int idx = tid; idx < F_IN * H; idx += 256) {
        int f = idx & (H - 1);
        int k = idx >> 5;
        Wt[k * H + f] = W1[f * F_IN + k];
    }
    int n0 = blockIdx.x * 8;
    for (int idx = tid; idx < 8 * F_IN; idx += 256) {
        int nl = idx >> 6, k = idx & 63;
        int n = n0 + nl;
        xs[idx] = (n < N_NODES) ? x[n * F_IN + k] : 0.f;
    }
    __syncthreads();
    int nl = tid >> 5, f = tid & 31;
    int n = n0 + nl;
    if (n < N_NODES) {
        float acc = 0.f;
#pragma unroll
        for (int k = 0; k < F_IN; ++k) acc += xs[nl * F_IN + k] * Wt[k * H + f];
        y[n * H + f] = acc;
    }
}

// block-level exclusive scan (in place on rowptr), block totals to bsum
__global__ __launch_bounds__(256) void k_scan1(
    int* __restrict__ rowptr, int* __restrict__ bsum)
{
    __shared__ int s[256];
    int i = blockIdx.x * 256 + threadIdx.x;
    int v = (i < N_NODES) ? rowptr[i] : 0;
    s[threadIdx.x] = v;
    __syncthreads();
    for (int off = 1; off < 256; off <<= 1) {
        int t = (threadIdx.x >= off) ? s[threadIdx.x - off] : 0;
        __syncthreads();
        s[threadIdx.x] += t;
        __syncthreads();
    }
    if (i < N_NODES) rowptr[i] = s[threadIdx.x] - v;   // exclusive within block
    if (threadIdx.x == 255) bsum[blockIdx.x] = s[255];
}

// scan2 folded in: each block locally exclusive-scans bsum (nb<=512) in LDS,
// then applies offsets; init cursor; rowptr[N]=E; zero gpool.
__global__ __launch_bounds__(256) void k_scan3(
    int* __restrict__ rowptr, const int* __restrict__ bsum, int nb,
    int* __restrict__ cursor, float* __restrict__ gpool)
{
    __shared__ int sb[512];
    int tid = threadIdx.x;
    for (int j = tid; j < nb; j += 256) sb[j] = bsum[j];
    __syncthreads();
    if (tid == 0) {
        int run = 0;
        for (int j = 0; j < nb; ++j) { int t = sb[j]; sb[j] = run; run += t; }
    }
    __syncthreads();
    int i = blockIdx.x * 256 + tid;
    if (i < N_NODES) {
        int r = rowptr[i] + sb[i >> 8];
        rowptr[i] = r;
        cursor[i] = r;
    }
    if (i == 0) rowptr[N_NODES] = N_EDGES;
    if (i < G * H) gpool[i] = 0.f;
}

// ---- partitioned scatter (verified r17: WRITE_SIZE 106MB -> merged; block b
// owns dst-partition (b&7), scans edge chunk (b>>3); partition's elist range
// stays resident in one XCD's L2 so 4B stores merge into full lines).
__global__ __launch_bounds__(256) void k_scatter(
    const int* __restrict__ ei, int* __restrict__ cursor,
    int* __restrict__ elist)
{
    int p    = blockIdx.x & (NPART - 1);
    int lo   = p * NODES_PER_P;
    int hi   = lo + NODES_PER_P;
    int base = (blockIdx.x >> 3) * EPB;
    for (int i = threadIdx.x; i < EPB; i += 256) {
        int e = base + i;
        if (e < N_EDGES) {
            int d = ei[N_EDGES + e];
            if (d >= lo && d < hi) {
                int pos = atomicAdd(&cursor[d], 1);
                elist[pos] = ei[e];
            }
        }
    }
}

// ======== fused agg + MLP, layer 0 ========
// 8 nodes/block, 32 lanes/node (scalar float, one 128B line per neighbor).
// 2 nodes/wave -> divergence tail = max-of-2 degree draws (+11%) vs
// r17's 4 nodes/wave (+24%).
__global__ __launch_bounds__(256) void k_aggmlp0(
    const int* __restrict__ rowptr, const int* __restrict__ elist,
    const float* __restrict__ y,
    const float* __restrict__ b1, const float* __restrict__ W2,
    const float* __restrict__ b2,
    const float* __restrict__ gamma, const float* __restrict__ beta,
    const float* __restrict__ mean,  const float* __restrict__ var,
    const float* __restrict__ nW,
    float* __restrict__ y_out)
{
    __shared__ float W2t[H * H];     // [k][f]
    __shared__ float nWt[H * H];     // [k][f]
    __shared__ float tb[8][H + 1];   // +1 pad
    __shared__ float hb[8][H + 1];
    int tid = threadIdx.x;
    for (int idx = tid; idx < H * H; idx += 256) {
        int f = idx & 31, k = idx >> 5;
        W2t[k * H + f] = W2[f * H + k];
        nWt[k * H + f] = nW[f * H + k];
    }
    int nl = tid >> 5;           // node-in-block 0..7
    int q  = tid & 31;           // feature slot
    int n  = blockIdx.x * 8 + nl;
    bool ok = n < N_NODES;

    float a = 0.f, b = 0.f, c = 0.f, d = 0.f;
    if (ok) {
        int j  = rowptr[n];
        int j1 = rowptr[n + 1];
        a = y[n * H + q];                      // self term
        for (; j + 4 <= j1; j += 4) {
            int s0 = elist[j],     s1 = elist[j + 1];
            int s2 = elist[j + 2], s3 = elist[j + 3];
            a += y[s0 * H + q];
            b += y[s1 * H + q];
            c += y[s2 * H + q];
            d += y[s3 * H + q];
        }
        for (; j < j1; ++j) a += y[elist[j] * H + q];
        a += b + c + d;
    }
    tb[nl][q] = fmaxf(a + b1[q], 0.f);
    __syncthreads();

    float z = b2[q];
#pragma unroll
    for (int k = 0; k < H; ++k) z = fmaf(tb[nl][k], W2t[k * H + q], z);
    z = fmaxf(z, 0.f);
    float s = gamma[q] * rsqrtf(var[q] + BN_EPS);
    hb[nl][q] = (z - mean[q]) * s + beta[q];
    __syncthreads();

    float yv = 0.f;
#pragma unroll
    for (int k = 0; k < H; ++k) yv = fmaf(hb[nl][k], nWt[k * H + q], yv);
    if (ok) y_out[n * H + q] = yv;
}

// ======== fused agg + MLP + global_add_pool, layer 1 ========
__global__ __launch_bounds__(256) void k_aggmlp1_pool(
    const int* __restrict__ rowptr, const int* __restrict__ elist,
    const float* __restrict__ y, const int* __restrict__ batch,
    const float* __restrict__ b1, const float* __restrict__ W2,
    const float* __restrict__ b2,
    const float* __restrict__ gamma, const float* __restrict__ beta,
    const float* __restrict__ mean,  const float* __restrict__ var,
    float* __restrict__ gpool)
{
    __shared__ float W2t[H * H];
    __shared__ float tb[8][H + 1];
    __shared__ float hb[8][H + 1];
    __shared__ int   bs[8];
    int tid = threadIdx.x;
    for (int idx = tid; idx < H * H; idx += 256) {
        int f = idx & 31, k = idx >> 5;
        W2t[k * H + f] = W2[f * H + k];
    }
    int nl = tid >> 5;
    int q  = tid & 31;
    int n  = blockIdx.x * 8 + nl;
    bool ok = n < N_NODES;
    if (tid < 8) {
        int nn = blockIdx.x * 8 + tid;
        bs[tid] = (nn < N_NODES) ? batch[nn] : -1;
    }

    float a = 0.f, b = 0.f, c = 0.f, d = 0.f;
    if (ok) {
        int j  = rowptr[n];
        int j1 = rowptr[n + 1];
        a = y[n * H + q];
        for (; j + 4 <= j1; j += 4) {
            int s0 = elist[j],     s1 = elist[j + 1];
            int s2 = elist[j + 2], s3 = elist[j + 3];
            a += y[s0 * H + q];
            b += y[s1 * H + q];
            c += y[s2 * H + q];
            d += y[s3 * H + q];
        }
        for (; j < j1; ++j) a += y[elist[j] * H + q];
        a += b + c + d;
    }
    tb[nl][q] = fmaxf(a + b1[q], 0.f);
    __syncthreads();

    float z = b2[q];
#pragma unroll
    for (int k = 0; k < H; ++k) z = fmaf(tb[nl][k], W2t[k * H + q], z);
    z = fmaxf(z, 0.f);
    float s = gamma[q] * rsqrtf(var[q] + BN_EPS);
    hb[nl][q] = (z - mean[q]) * s + beta[q];
    __syncthreads();

    // segment-head combining (batch sorted): one atomic per (segment, f)
    if (ok && (nl == 0 || bs[nl] != bs[nl - 1])) {
        int bid = bs[nl];
        float acc = hb[nl][q];
        for (int j = nl + 1; j < 8 && bs[j] == bid; ++j) acc += hb[j][q];
        atomicAdd(&gpool[bid * H + q], acc);
    }
}

// -------------------- g -> relu(fc1) -> fc2 -> seq[G*C]
__global__ __launch_bounds__(256) void k_fc(
    const float* __restrict__ gpool,
    const float* __restrict__ fc1W, const float* __restrict__ fc1b,
    const float* __restrict__ fc2W, const float* __restrict__ fc2b,
    float* __restrict__ seq)
{
    __shared__ float W1t[H * H];
    __shared__ float gs[8][H];
    __shared__ float tb[8][H];
    int tid = threadIdx.x;
    for (int idx = tid; idx < H * H; idx += 256) {
        int f = idx & 31, k = idx >> 5;
        W1t[k * H + f] = fc1W[f * H + k];
    }
    int n0 = blockIdx.x * 8;
    int nl = tid >> 5, f = tid & 31;
    int g = n0 + nl;
    bool ok = g < G;
    gs[nl][f] = ok ? gpool[g * H + f] : 0.f;
    __syncthreads();
    float z = fc1b[f];
#pragma unroll
    for (int k = 0; k < H; ++k) z += gs[nl][k] * W1t[k * H + f];
    tb[nl][f] = fmaxf(z, 0.f);
    __syncthreads();
    if (ok && f < C) {
        float z2 = fc2b[f];
#pragma unroll
        for (int k = 0; k < H; ++k) z2 += tb[nl][k] * fc2W[f * H + k];
        seq[g * C + f] = z2;
    }
}

// ---------- wave-synchronous bidirectional LSTM ----------
// Gate exchange via v_permlane32_swap_b32 (pure VALU) — verified r15.

#if __has_builtin(__builtin_amdgcn_readlane)
#define RDL(v, k) __int_as_float(__builtin_amdgcn_readlane(__float_as_int(v), (k)))
#else
#define RDL(v, k) __shfl((v), (k), 64)
#endif

#define LOG2E  1.4426950408889634f
#define N2L2E  2.8853900817779268f

#if __has_builtin(__builtin_amdgcn_exp2f) && __has_builtin(__builtin_amdgcn_rcpf)
#define EXP2F(x) __builtin_amdgcn_exp2f(x)
#define RCPF(x)  __builtin_amdgcn_rcpf(x)
#else
#define EXP2F(x) exp2f(x)
#define RCPF(x)  (1.f / (x))
#endif

__device__ __forceinline__ float fsig(float x) {   // 1/(1+e^-x)
    return RCPF(1.f + EXP2F(-LOG2E * x));
}
__device__ __forceinline__ float ftanh(float x) {  // 2/(1+e^-2x) - 1
    return 2.f * RCPF(1.f + EXP2F(-N2L2E * x)) - 1.f;
}

#define PIN4(v) asm("" : "+v"((v).x), "+v"((v).y), "+v"((v).z), "+v"((v).w))

// d_lo = src lanes 0..31 replicated to all; d_hi = src lanes 32..63 replicated.
#define SPLIT(d_lo, d_hi, src)                                            \
    asm("v_mov_b32 %0, %2\n\t"                                            \
        "v_mov_b32 %1, %2\n\t"                                            \
        "v_permlane32_swap_b32 %0, %1"                                    \
        : "=&v"(d_lo), "=&v"(d_hi)                                        \
        : "v"(src));

#define ACC4_(av, bv, hA, hB, hC, hD)                                     \
    z0 = fmaf((av).x, hA, z0); z1 = fmaf((av).y, hB, z1);                 \
    z2 = fmaf((av).z, hC, z2); z3 = fmaf((av).w, hD, z3);                 \
    y0 = fmaf((bv).x, hA, y0); y1 = fmaf((bv).y, hB, y1);                 \
    y2 = fmaf((bv).z, hC, y2); y3 = fmaf((bv).w, hD, y3);

__global__ __launch_bounds__(128, 1) void k_lstm(
    const float* __restrict__ seq,
    const float* __restrict__ Wih_f, const float* __restrict__ Whh_f,
    const float* __restrict__ bih_f, const float* __restrict__ bhh_f,
    const float* __restrict__ Wih_b, const float* __restrict__ Whh_b,
    const float* __restrict__ bih_b, const float* __restrict__ bhh_b,
    const float* __restrict__ redW, const float* __restrict__ redb,
    float* __restrict__ out)
{
    __shared__ float  sq[G * C];
    __shared__ float  hl[2][H];
    __shared__ float4 wl4[2048];   // [dir][ab][k4][lane] float4 = 32 KB
    int tid  = threadIdx.x;
    int dir  = tid >> 6;
    int lane = tid & 63;

    for (int i = tid; i < G * C; i += 128) sq[i] = seq[i];
    for (int i = tid; i < 2048; i += 128) {
        int d  = i >> 10;
        int r  = i & 1023;
        int ab = r >> 9;
        int k4 = (r >> 6) & 7;
        int l  = r & 63;
        const float4* src4 = (const float4*)(d ? Whh_b : Whh_f);
        wl4[i] = src4[(ab * 64 + l) * 8 + k4];
    }
    __syncthreads();

    const float* Wih = dir ? Wih_b : Wih_f;
    const float* bih = dir ? bih_b : bih_f;
    const float* bhh = dir ? bhh_b : bhh_f;

    int ra = lane;
    int rb = lane + 64;

    const float4* wA = &wl4[dir * 1024];
    const float4* wB = &wl4[dir * 1024 + 512];

    float4 a0 = wA[0 * 64 + lane], a1 = wA[1 * 64 + lane];
    float4 a2 = wA[2 * 64 + lane], a3 = wA[3 * 64 + lane];
    float4 a4 = wA[4 * 64 + lane], a5 = wA[5 * 64 + lane];
    float4 a6 = wA[6 * 64 + lane], a7 = wA[7 * 64 + lane];
    float4 b0 = wB[0 * 64 + lane], b1 = wB[1 * 64 + lane];
    float4 b2 = wB[2 * 64 + lane], b3 = wB[3 * 64 + lane];
    float4 b4 = wB[4 * 64 + lane], b5 = wB[5 * 64 + lane];
    float4 b6 = wB[6 * 64 + lane], b7 = wB[7 * 64 + lane];
    PIN4(a0); PIN4(a1); PIN4(a2); PIN4(a3);
    PIN4(a4); PIN4(a5); PIN4(a6); PIN4(a7);
    PIN4(b0); PIN4(b1); PIN4(b2); PIN4(b3);
    PIN4(b4); PIN4(b5); PIN4(b6); PIN4(b7);

    float wia0 = Wih[ra * C], wia1 = Wih[ra * C + 1];
    float wib0 = Wih[rb * C], wib1 = Wih[rb * C + 1];
    float bza  = bih[ra] + bhh[ra];
    float bzb  = bih[rb] + bhh[rb];

    float hval = 0.f;
    float cst  = 0.f;

    int tt0 = dir ? (G - 1) : 0;
    float x0 = sq[tt0 * C];
    float x1 = sq[tt0 * C + 1];

#pragma unroll 2
    for (int t = 0; t < G; ++t) {
        int tn = (t + 1 < G) ? (dir ? (G - 2 - t) : (t + 1)) : 0;
        float nx0 = sq[tn * C];
        float nx1 = sq[tn * C + 1];

        float h0  = RDL(hval, 0),  h1  = RDL(hval, 1);
        float h2  = RDL(hval, 2),  h3  = RDL(hval, 3);
        float h4  = RDL(hval, 4),  h5  = RDL(hval, 5);
        float h6  = RDL(hval, 6),  h7  = RDL(hval, 7);
        float h8  = RDL(hval, 8),  h9  = RDL(hval, 9);
        float h10 = RDL(hval, 10), h11 = RDL(hval, 11);
        float h12 = RDL(hval, 12), h13 = RDL(hval, 13);
        float h14 = RDL(hval, 14), h15 = RDL(hval, 15);
        float h16 = RDL(hval, 16), h17 = RDL(hval, 17);
        float h18 = RDL(hval, 18), h19 = RDL(hval, 19);
        float h20 = RDL(hval, 20), h21 = RDL(hval, 21);
        float h22 = RDL(hval, 22), h23 = RDL(hval, 23);
        float h24 = RDL(hval, 24), h25 = RDL(hval, 25);
        float h26 = RDL(hval, 26), h27 = RDL(hval, 27);
        float h28 = RDL(hval, 28), h29 = RDL(hval, 29);
        float h30 = RDL(hval, 30), h31 = RDL(hval, 31);

        float z0 = 0.f, z1 = 0.f, z2 = 0.f, z3 = 0.f;
        float y0 = 0.f, y1 = 0.f, y2 = 0.f, y3 = 0.f;
        ACC4_(a0, b0, h0,  h1,  h2,  h3);
        ACC4_(a1, b1, h4,  h5,  h6,  h7);
        ACC4_(a2, b2, h8,  h9,  h10, h11);
        ACC4_(a3, b3, h12, h13, h14, h15);
        ACC4_(a4, b4, h16, h17, h18, h19);
        ACC4_(a5, b5, h20, h21, h22, h23);
        ACC4_(a6, b6, h24, h25, h26, h27);
        ACC4_(a7, b7, h28, h29, h30, h31);

        float za = bza + fmaf(wia0, x0, fmaf(wia1, x1, (z0 + z1) + (z2 + z3)));
        float zb = bzb + fmaf(wib0, x0, fmaf(wib1, x1, (y0 + y1) + (y2 + y3)));

        // za: lanes 0..31 = i-rows, lanes 32..63 = f-rows
        // zb: lanes 0..31 = g-rows, lanes 32..63 = o-rows
        float zi, zf, zg, zo;
        SPLIT(zi, zf, za);   // zi = lo half replicated, zf = hi half
        SPLIT(zg, zo, zb);   // zg = lo half replicated, zo = hi half

        cst  = fsig(zf) * cst + fsig(zi) * ftanh(zg);
        hval = fsig(zo) * ftanh(cst);

        x0 = nx0; x1 = nx1;
    }

    if (lane < H) hl[dir][lane] = hval;
    __syncthreads();

    if (tid == 0) {
        float v0 = redb[0], v1 = redb[1];
        for (int k = 0; k < H; ++k) {
            v0 += hl[0][k] * redW[k]         + hl[1][k] * redW[H + k];
            v1 += hl[0][k] * redW[2 * H + k] + hl[1][k] * redW[3 * H + k];
        }
        v0 = fmaxf(v0, 0.f);
        v1 = fmaxf(v1, 0.f);
        float m = fmaxf(v0, v1);
        float l = logf(expf(v0 - m) + expf(v1 - m));
        out[0] = v0 - m - l;
        out[1] = v1 - m - l;
    }
}

extern "C" void kernel_launch(void* const* d_in, const int* in_sizes, int n_in,
                              void* d_out, int out_size, void* d_ws, size_t ws_size,
                              hipStream_t stream) {
    const float* x        = (const float*)d_in[0];
    const int*   ei       = (const int*)  d_in[1];
    const int*   batch    = (const int*)  d_in[2];
    const float* gin0_W1  = (const float*)d_in[3];
    const float* gin0_b1  = (const float*)d_in[4];
    const float* gin0_W2  = (const float*)d_in[5];
    const float* gin0_b2  = (const float*)d_in[6];
    const float* bn0_g    = (const float*)d_in[7];
    const float* bn0_b    = (const float*)d_in[8];
    const float* bn0_m    = (const float*)d_in[9];
    const float* bn0_v    = (const float*)d_in[10];
    const float* gin1_W1  = (const float*)d_in[11];
    const float* gin1_b1  = (const float*)d_in[12];
    const float* gin1_W2  = (const float*)d_in[13];
    const float* gin1_b2  = (const float*)d_in[14];
    const float* bn1_g    = (const float*)d_in[15];
    const float* bn1_b    = (const float*)d_in[16];
    const float* bn1_m    = (const float*)d_in[17];
    const float* bn1_v    = (const float*)d_in[18];
    const float* fc1_W    = (const float*)d_in[19];
    const float* fc1_b    = (const float*)d_in[20];
    const float* fc2_W    = (const float*)d_in[21];
    const float* fc2_b    = (const float*)d_in[22];
    const float* Wih_f    = (const float*)d_in[23];
    const float* Whh_f    = (const float*)d_in[24];
    const float* bih_f    = (const float*)d_in[25];
    const float* bhh_f    = (const float*)d_in[26];
    const float* Wih_b    = (const float*)d_in[27];
    const float* Whh_b    = (const float*)d_in[28];
    const float* bih_b    = (const float*)d_in[29];
    const float* bhh_b    = (const float*)d_in[30];
    const float* red_W    = (const float*)d_in[31];
    const float* red_b    = (const float*)d_in[32];

    // workspace layout
    float* ws    = (float*)d_ws;
    float* A     = ws;                          // y buffer   N*H
    float* B     = A + (size_t)N_NODES * H;     // y1 buffer  N*H
    float* gpool = B + (size_t)N_NODES * H;     // G*H
    float* seq   = gpool + (size_t)G * H;       // G*C
    int*   rowptr = (int*)(seq + (size_t)G * C);        // N+1
    int*   cursor = rowptr + (N_NODES + 1);             // N
    int*   bsum   = cursor + N_NODES;                   // 1024
    int*   elist  = bsum + 1024;                        // E

    int nblk_x       = (N_NODES + 7) / 8;          // 12500 (xform0 blocks)
    int nblk_edges   = (N_EDGES + 255) / 256;      // 6250
    int nblk_scan    = (N_NODES + 255) / 256;      // 391
    int nblk_fuse    = (N_NODES + 7) / 8;          // 12500 (8 nodes/block)
    int nblk_scatter = ((N_EDGES + EPB - 1) / EPB) * NPART;  // 782*8 = 6256

    // ---- CSR build + xform0 (fused: independent work, one dispatch)
    k_zero_i<<<nblk_scan, 256, 0, stream>>>(rowptr, N_NODES);
    k_histx<<<nblk_x + nblk_edges, 256, 0, stream>>>(ei, rowptr, x, gin0_W1,
                                                     A, nblk_x);
    k_scan1<<<nblk_scan, 256, 0, stream>>>(rowptr, bsum);
    k_scan3<<<nblk_scan, 256, 0, stream>>>(rowptr, bsum, nblk_scan, cursor, gpool);
    k_scatter<<<nblk_scatter, 256, 0, stream>>>(ei, cursor, elist);

    // ---- layer 0 (fused agg+mlp, writes next-layer y1 into B)
    k_aggmlp0<<<nblk_fuse, 256, 0, stream>>>(rowptr, elist, A,
                                             gin0_b1, gin0_W2, gin0_b2,
                                             bn0_g, bn0_b, bn0_m, bn0_v,
                                             gin1_W1, B);
    // ---- layer 1 (fused agg+mlp+pool)
    k_aggmlp1_pool<<<nblk_fuse, 256, 0, stream>>>(rowptr, elist, B, batch,
                                                  gin1_b1, gin1_W2, gin1_b2,
                                                  bn1_g, bn1_b, bn1_m, bn1_v,
                                                  gpool);
    // ---- dense tail
    k_fc<<<(G + 7) / 8, 256, 0, stream>>>(gpool, fc1_W, fc1_b, fc2_W, fc2_b, seq);
    k_lstm<<<1, 128, 0, stream>>>(seq, Wih_f, Whh_f, bih_f, bhh_f,
                                  Wih_b, Whh_b, bih_b, bhh_b,
                                  red_W, red_b, (float*)d_out);
}

// Round 19
// 443.846 us; speedup vs baseline: 1.0969x; 1.0969x over previous
//
#include <hip/hip_runtime.h>
#include <math.h>

#define N_NODES 100000
#define N_EDGES 1600000
#define F_IN    64
#define H       32
#define C       2
#define G       500
#define BN_EPS  1e-5f

#define NPART        8        // dst partitions == XCD count
#define NODES_PER_P  12500    // 100000 / 8
#define EPB          2048     // edges scanned per block in k_scatter

// ---------------------------------------------------------------- zero utils
__global__ __launch_bounds__(256) void k_zero_i(int* __restrict__ p, int n) {
    int i = blockIdx.x * 256 + threadIdx.x;
    if (i < n) p[i] = 0;
}

// ---- fused: xform0 (blocks [0,nblk_x)) + histogram (rest). Independent work
// sharing one dispatch: hides xform0's serial time under hist's atomics.
__global__ __launch_bounds__(256) void k_histx(
    const int* __restrict__ ei, int* __restrict__ deg,
    const float* __restrict__ x, const float* __restrict__ W1,
    float* __restrict__ y, int nblk_x)
{
    __shared__ float Wt[F_IN * H];   // Wt[k*H+f] = W1[f*F_IN+k]
    __shared__ float xs[8 * F_IN];
    int tid = threadIdx.x;
    if ((int)blockIdx.x >= nblk_x) {
        // ---- histogram part
        int e = ((int)blockIdx.x - nblk_x) * 256 + tid;
        if (e < N_EDGES) atomicAdd(&deg[ei[N_EDGES + e]], 1);
        return;
    }
    // ---- xform0 part: y0 = x @ W1^T (8 nodes/block)
    for (int idx = tid; idx < F_IN * H; idx += 256) {
        int f = idx & (H - 1);
        int k = idx >> 5;
        Wt[k * H + f] = W1[f * F_IN + k];
    }
    int n0 = blockIdx.x * 8;
    for (int idx = tid; idx < 8 * F_IN; idx += 256) {
        int nl = idx >> 6, k = idx & 63;
        int n = n0 + nl;
        xs[idx] = (n < N_NODES) ? x[n * F_IN + k] : 0.f;
    }
    __syncthreads();
    int nl = tid >> 5, f = tid & 31;
    int n = n0 + nl;
    if (n < N_NODES) {
        float acc = 0.f;
#pragma unroll
        for (int k = 0; k < F_IN; ++k) acc += xs[nl * F_IN + k] * Wt[k * H + f];
        y[n * H + f] = acc;
    }
}

// block-level exclusive scan (in place on rowptr), block totals to bsum
__global__ __launch_bounds__(256) void k_scan1(
    int* __restrict__ rowptr, int* __restrict__ bsum)
{
    __shared__ int s[256];
    int i = blockIdx.x * 256 + threadIdx.x;
    int v = (i < N_NODES) ? rowptr[i] : 0;
    s[threadIdx.x] = v;
    __syncthreads();
    for (int off = 1; off < 256; off <<= 1) {
        int t = (threadIdx.x >= off) ? s[threadIdx.x - off] : 0;
        __syncthreads();
        s[threadIdx.x] += t;
        __syncthreads();
    }
    if (i < N_NODES) rowptr[i] = s[threadIdx.x] - v;   // exclusive within block
    if (threadIdx.x == 255) bsum[blockIdx.x] = s[255];
}

// scan2 folded in: each block locally exclusive-scans bsum (nb<=512) in LDS,
// then applies offsets; init cursor; rowptr[N]=E; zero gpool.
__global__ __launch_bounds__(256) void k_scan3(
    int* __restrict__ rowptr, const int* __restrict__ bsum, int nb,
    int* __restrict__ cursor, float* __restrict__ gpool)
{
    __shared__ int sb[512];
    int tid = threadIdx.x;
    for (int j = tid; j < nb; j += 256) sb[j] = bsum[j];
    __syncthreads();
    if (tid == 0) {
        int run = 0;
        for (int j = 0; j < nb; ++j) { int t = sb[j]; sb[j] = run; run += t; }
    }
    __syncthreads();
    int i = blockIdx.x * 256 + tid;
    if (i < N_NODES) {
        int r = rowptr[i] + sb[i >> 8];
        rowptr[i] = r;
        cursor[i] = r;
    }
    if (i == 0) rowptr[N_NODES] = N_EDGES;
    if (i < G * H) gpool[i] = 0.f;
}

// ---- partitioned scatter (verified r17: block b owns dst-partition (b&7),
// scans edge chunk (b>>3); partition's elist range stays resident in one
// XCD's L2 so 4B stores merge into full lines).
__global__ __launch_bounds__(256) void k_scatter(
    const int* __restrict__ ei, int* __restrict__ cursor,
    int* __restrict__ elist)
{
    int p    = blockIdx.x & (NPART - 1);
    int lo   = p * NODES_PER_P;
    int hi   = lo + NODES_PER_P;
    int base = (blockIdx.x >> 3) * EPB;
    for (int i = threadIdx.x; i < EPB; i += 256) {
        int e = base + i;
        if (e < N_EDGES) {
            int d = ei[N_EDGES + e];
            if (d >= lo && d < hi) {
                int pos = atomicAdd(&cursor[d], 1);
                elist[pos] = ei[e];
            }
        }
    }
}

// ======== fused agg + MLP, layer 0 (r17-verified form) ========
// 16 nodes/block, 16 lanes/node (float2 = 8B/lane — instruction-count
// efficient; r18's scalar 4B/lane variant regressed 36us total).
__global__ __launch_bounds__(256) void k_aggmlp0(
    const int* __restrict__ rowptr, const int* __restrict__ elist,
    const float* __restrict__ y,
    const float* __restrict__ b1, const float* __restrict__ W2,
    const float* __restrict__ b2,
    const float* __restrict__ gamma, const float* __restrict__ beta,
    const float* __restrict__ mean,  const float* __restrict__ var,
    const float* __restrict__ nW,
    float* __restrict__ y_out)
{
    __shared__ float W2t[H * H];     // [k][f]
    __shared__ float nWt[H * H];     // [k][f]
    __shared__ float tb[16][H + 1];  // +1 pad: kill 4-way bank conflict
    __shared__ float hb[16][H + 1];
    int tid = threadIdx.x;
    for (int idx = tid; idx < H * H; idx += 256) {
        int f = idx & 31, k = idx >> 5;
        W2t[k * H + f] = W2[f * H + k];
        nWt[k * H + f] = nW[f * H + k];
    }
    int nl = tid >> 4;           // node-in-block 0..15
    int q  = tid & 15;           // float2 slot
    int n  = blockIdx.x * 16 + nl;
    bool ok = n < N_NODES;

    float2 a = make_float2(0.f, 0.f), b = a, c = a, d = a;
    if (ok) {
        int j  = rowptr[n];
        int j1 = rowptr[n + 1];
        const float2* y2 = (const float2*)y;
        a = y2[n * 16 + q];                     // self term
        for (; j + 4 <= j1; j += 4) {
            int s0 = elist[j],     s1 = elist[j + 1];
            int s2 = elist[j + 2], s3 = elist[j + 3];
            float2 v0 = y2[s0 * 16 + q];
            float2 v1 = y2[s1 * 16 + q];
            float2 v2 = y2[s2 * 16 + q];
            float2 v3 = y2[s3 * 16 + q];
            a.x += v0.x; a.y += v0.y;
            b.x += v1.x; b.y += v1.y;
            c.x += v2.x; c.y += v2.y;
            d.x += v3.x; d.y += v3.y;
        }
        for (; j < j1; ++j) {
            int s0 = elist[j];
            float2 v0 = y2[s0 * 16 + q];
            a.x += v0.x; a.y += v0.y;
        }
        a.x += b.x + c.x + d.x;
        a.y += b.y + c.y + d.y;
    }
    tb[nl][2 * q]     = fmaxf(a.x + b1[2 * q],     0.f);
    tb[nl][2 * q + 1] = fmaxf(a.y + b1[2 * q + 1], 0.f);
    __syncthreads();

    // each thread: outputs f=q and f=q+16 for node nl
    float z0 = b2[q], z1 = b2[q + 16];
#pragma unroll
    for (int k = 0; k < H; ++k) {
        float tk = tb[nl][k];
        z0 = fmaf(tk, W2t[k * H + q],      z0);
        z1 = fmaf(tk, W2t[k * H + q + 16], z1);
    }
    z0 = fmaxf(z0, 0.f);
    z1 = fmaxf(z1, 0.f);
    float s0 = gamma[q]      * rsqrtf(var[q]      + BN_EPS);
    float s1 = gamma[q + 16] * rsqrtf(var[q + 16] + BN_EPS);
    hb[nl][q]      = (z0 - mean[q])      * s0 + beta[q];
    hb[nl][q + 16] = (z1 - mean[q + 16]) * s1 + beta[q + 16];
    __syncthreads();

    float yv0 = 0.f, yv1 = 0.f;
#pragma unroll
    for (int k = 0; k < H; ++k) {
        float hk = hb[nl][k];
        yv0 = fmaf(hk, nWt[k * H + q],      yv0);
        yv1 = fmaf(hk, nWt[k * H + q + 16], yv1);
    }
    if (ok) {
        y_out[n * H + q]      = yv0;
        y_out[n * H + q + 16] = yv1;
    }
}

// ======== fused agg + MLP + global_add_pool, layer 1 (r17-verified) ========
__global__ __launch_bounds__(256) void k_aggmlp1_pool(
    const int* __restrict__ rowptr, const int* __restrict__ elist,
    const float* __restrict__ y, const int* __restrict__ batch,
    const float* __restrict__ b1, const float* __restrict__ W2,
    const float* __restrict__ b2,
    const float* __restrict__ gamma, const float* __restrict__ beta,
    const float* __restrict__ mean,  const float* __restrict__ var,
    float* __restrict__ gpool)
{
    __shared__ float W2t[H * H];
    __shared__ float tb[16][H + 1];
    __shared__ float hb[16][H + 1];
    __shared__ int   bs[16];
    int tid = threadIdx.x;
    for (int idx = tid; idx < H * H; idx += 256) {
        int f = idx & 31, k = idx >> 5;
        W2t[k * H + f] = W2[f * H + k];
    }
    int nl = tid >> 4;
    int q  = tid & 15;
    int n  = blockIdx.x * 16 + nl;
    bool ok = n < N_NODES;
    if (tid < 16) {
        int nn = blockIdx.x * 16 + tid;
        bs[tid] = (nn < N_NODES) ? batch[nn] : -1;
    }

    float2 a = make_float2(0.f, 0.f), b = a, c = a, d = a;
    if (ok) {
        int j  = rowptr[n];
        int j1 = rowptr[n + 1];
        const float2* y2 = (const float2*)y;
        a = y2[n * 16 + q];
        for (; j + 4 <= j1; j += 4) {
            int s0 = elist[j],     s1 = elist[j + 1];
            int s2 = elist[j + 2], s3 = elist[j + 3];
            float2 v0 = y2[s0 * 16 + q];
            float2 v1 = y2[s1 * 16 + q];
            float2 v2 = y2[s2 * 16 + q];
            float2 v3 = y2[s3 * 16 + q];
            a.x += v0.x; a.y += v0.y;
            b.x += v1.x; b.y += v1.y;
            c.x += v2.x; c.y += v2.y;
            d.x += v3.x; d.y += v3.y;
        }
        for (; j < j1; ++j) {
            int s0 = elist[j];
            float2 v0 = y2[s0 * 16 + q];
            a.x += v0.x; a.y += v0.y;
        }
        a.x += b.x + c.x + d.x;
        a.y += b.y + c.y + d.y;
    }
    tb[nl][2 * q]     = fmaxf(a.x + b1[2 * q],     0.f);
    tb[nl][2 * q + 1] = fmaxf(a.y + b1[2 * q + 1], 0.f);
    __syncthreads();

    float z0 = b2[q], z1 = b2[q + 16];
#pragma unroll
    for (int k = 0; k < H; ++k) {
        float tk = tb[nl][k];
        z0 = fmaf(tk, W2t[k * H + q],      z0);
        z1 = fmaf(tk, W2t[k * H + q + 16], z1);
    }
    z0 = fmaxf(z0, 0.f);
    z1 = fmaxf(z1, 0.f);
    float s0 = gamma[q]      * rsqrtf(var[q]      + BN_EPS);
    float s1 = gamma[q + 16] * rsqrtf(var[q + 16] + BN_EPS);
    hb[nl][q]      = (z0 - mean[q])      * s0 + beta[q];
    hb[nl][q + 16] = (z1 - mean[q + 16]) * s1 + beta[q + 16];
    __syncthreads();

    // segment-head combining (batch sorted): one atomic per (segment, f)
    if (ok && (nl == 0 || bs[nl] != bs[nl - 1])) {
        int bid = bs[nl];
        float acc0 = hb[nl][q];
        float acc1 = hb[nl][q + 16];
        for (int j = nl + 1; j < 16 && bs[j] == bid; ++j) {
            acc0 += hb[j][q];
            acc1 += hb[j][q + 16];
        }
        atomicAdd(&gpool[bid * H + q],      acc0);
        atomicAdd(&gpool[bid * H + q + 16], acc1);
    }
}

// -------------------- g -> relu(fc1) -> fc2 -> seq[G*C]
__global__ __launch_bounds__(256) void k_fc(
    const float* __restrict__ gpool,
    const float* __restrict__ fc1W, const float* __restrict__ fc1b,
    const float* __restrict__ fc2W, const float* __restrict__ fc2b,
    float* __restrict__ seq)
{
    __shared__ float W1t[H * H];
    __shared__ float gs[8][H];
    __shared__ float tb[8][H];
    int tid = threadIdx.x;
    for (int idx = tid; idx < H * H; idx += 256) {
        int f = idx & 31, k = idx >> 5;
        W1t[k * H + f] = fc1W[f * H + k];
    }
    int n0 = blockIdx.x * 8;
    int nl = tid >> 5, f = tid & 31;
    int g = n0 + nl;
    bool ok = g < G;
    gs[nl][f] = ok ? gpool[g * H + f] : 0.f;
    __syncthreads();
    float z = fc1b[f];
#pragma unroll
    for (int k = 0; k < H; ++k) z += gs[nl][k] * W1t[k * H + f];
    tb[nl][f] = fmaxf(z, 0.f);
    __syncthreads();
    if (ok && f < C) {
        float z2 = fc2b[f];
#pragma unroll
        for (int k = 0; k < H; ++k) z2 += tb[nl][k] * fc2W[f * H + k];
        seq[g * C + f] = z2;
    }
}

// ---------- wave-synchronous bidirectional LSTM ----------
// Gate exchange via v_permlane32_swap_b32 (pure VALU) — verified r15.

#if __has_builtin(__builtin_amdgcn_readlane)
#define RDL(v, k) __int_as_float(__builtin_amdgcn_readlane(__float_as_int(v), (k)))
#else
#define RDL(v, k) __shfl((v), (k), 64)
#endif

#define LOG2E  1.4426950408889634f
#define N2L2E  2.8853900817779268f

#if __has_builtin(__builtin_amdgcn_exp2f) && __has_builtin(__builtin_amdgcn_rcpf)
#define EXP2F(x) __builtin_amdgcn_exp2f(x)
#define RCPF(x)  __builtin_amdgcn_rcpf(x)
#else
#define EXP2F(x) exp2f(x)
#define RCPF(x)  (1.f / (x))
#endif

__device__ __forceinline__ float fsig(float x) {   // 1/(1+e^-x)
    return RCPF(1.f + EXP2F(-LOG2E * x));
}
__device__ __forceinline__ float ftanh(float x) {  // 2/(1+e^-2x) - 1
    return 2.f * RCPF(1.f + EXP2F(-N2L2E * x)) - 1.f;
}

#define PIN4(v) asm("" : "+v"((v).x), "+v"((v).y), "+v"((v).z), "+v"((v).w))

// d_lo = src lanes 0..31 replicated to all; d_hi = src lanes 32..63 replicated.
#define SPLIT(d_lo, d_hi, src)                                            \
    asm("v_mov_b32 %0, %2\n\t"                                            \
        "v_mov_b32 %1, %2\n\t"                                            \
        "v_permlane32_swap_b32 %0, %1"                                    \
        : "=&v"(d_lo), "=&v"(d_hi)                                        \
        : "v"(src));

#define ACC4_(av, bv, hA, hB, hC, hD)                                     \
    z0 = fmaf((av).x, hA, z0); z1 = fmaf((av).y, hB, z1);                 \
    z2 = fmaf((av).z, hC, z2); z3 = fmaf((av).w, hD, z3);                 \
    y0 = fmaf((bv).x, hA, y0); y1 = fmaf((bv).y, hB, y1);                 \
    y2 = fmaf((bv).z, hC, y2); y3 = fmaf((bv).w, hD, y3);

__global__ __launch_bounds__(128, 1) void k_lstm(
    const float* __restrict__ seq,
    const float* __restrict__ Wih_f, const float* __restrict__ Whh_f,
    const float* __restrict__ bih_f, const float* __restrict__ bhh_f,
    const float* __restrict__ Wih_b, const float* __restrict__ Whh_b,
    const float* __restrict__ bih_b, const float* __restrict__ bhh_b,
    const float* __restrict__ redW, const float* __restrict__ redb,
    float* __restrict__ out)
{
    __shared__ float  sq[G * C];
    __shared__ float  hl[2][H];
    __shared__ float4 wl4[2048];   // [dir][ab][k4][lane] float4 = 32 KB
    int tid  = threadIdx.x;
    int dir  = tid >> 6;
    int lane = tid & 63;

    for (int i = tid; i < G * C; i += 128) sq[i] = seq[i];
    for (int i = tid; i < 2048; i += 128) {
        int d  = i >> 10;
        int r  = i & 1023;
        int ab = r >> 9;
        int k4 = (r >> 6) & 7;
        int l  = r & 63;
        const float4* src4 = (const float4*)(d ? Whh_b : Whh_f);
        wl4[i] = src4[(ab * 64 + l) * 8 + k4];
    }
    __syncthreads();

    const float* Wih = dir ? Wih_b : Wih_f;
    const float* bih = dir ? bih_b : bih_f;
    const float* bhh = dir ? bhh_b : bhh_f;

    int ra = lane;
    int rb = lane + 64;

    const float4* wA = &wl4[dir * 1024];
    const float4* wB = &wl4[dir * 1024 + 512];

    float4 a0 = wA[0 * 64 + lane], a1 = wA[1 * 64 + lane];
    float4 a2 = wA[2 * 64 + lane], a3 = wA[3 * 64 + lane];
    float4 a4 = wA[4 * 64 + lane], a5 = wA[5 * 64 + lane];
    float4 a6 = wA[6 * 64 + lane], a7 = wA[7 * 64 + lane];
    float4 b0 = wB[0 * 64 + lane], b1 = wB[1 * 64 + lane];
    float4 b2 = wB[2 * 64 + lane], b3 = wB[3 * 64 + lane];
    float4 b4 = wB[4 * 64 + lane], b5 = wB[5 * 64 + lane];
    float4 b6 = wB[6 * 64 + lane], b7 = wB[7 * 64 + lane];
    PIN4(a0); PIN4(a1); PIN4(a2); PIN4(a3);
    PIN4(a4); PIN4(a5); PIN4(a6); PIN4(a7);
    PIN4(b0); PIN4(b1); PIN4(b2); PIN4(b3);
    PIN4(b4); PIN4(b5); PIN4(b6); PIN4(b7);

    float wia0 = Wih[ra * C], wia1 = Wih[ra * C + 1];
    float wib0 = Wih[rb * C], wib1 = Wih[rb * C + 1];
    float bza  = bih[ra] + bhh[ra];
    float bzb  = bih[rb] + bhh[rb];

    float hval = 0.f;
    float cst  = 0.f;

    int tt0 = dir ? (G - 1) : 0;
    float x0 = sq[tt0 * C];
    float x1 = sq[tt0 * C + 1];

#pragma unroll 2
    for (int t = 0; t < G; ++t) {
        int tn = (t + 1 < G) ? (dir ? (G - 2 - t) : (t + 1)) : 0;
        float nx0 = sq[tn * C];
        float nx1 = sq[tn * C + 1];

        float h0  = RDL(hval, 0),  h1  = RDL(hval, 1);
        float h2  = RDL(hval, 2),  h3  = RDL(hval, 3);
        float h4  = RDL(hval, 4),  h5  = RDL(hval, 5);
        float h6  = RDL(hval, 6),  h7  = RDL(hval, 7);
        float h8  = RDL(hval, 8),  h9  = RDL(hval, 9);
        float h10 = RDL(hval, 10), h11 = RDL(hval, 11);
        float h12 = RDL(hval, 12), h13 = RDL(hval, 13);
        float h14 = RDL(hval, 14), h15 = RDL(hval, 15);
        float h16 = RDL(hval, 16), h17 = RDL(hval, 17);
        float h18 = RDL(hval, 18), h19 = RDL(hval, 19);
        float h20 = RDL(hval, 20), h21 = RDL(hval, 21);
        float h22 = RDL(hval, 22), h23 = RDL(hval, 23);
        float h24 = RDL(hval, 24), h25 = RDL(hval, 25);
        float h26 = RDL(hval, 26), h27 = RDL(hval, 27);
        float h28 = RDL(hval, 28), h29 = RDL(hval, 29);
        float h30 = RDL(hval, 30), h31 = RDL(hval, 31);

        float z0 = 0.f, z1 = 0.f, z2 = 0.f, z3 = 0.f;
        float y0 = 0.f, y1 = 0.f, y2 = 0.f, y3 = 0.f;
        ACC4_(a0, b0, h0,  h1,  h2,  h3);
        ACC4_(a1, b1, h4,  h5,  h6,  h7);
        ACC4_(a2, b2, h8,  h9,  h10, h11);
        ACC4_(a3, b3, h12, h13, h14, h15);
        ACC4_(a4, b4, h16, h17, h18, h19);
        ACC4_(a5, b5, h20, h21, h22, h23);
        ACC4_(a6, b6, h24, h25, h26, h27);
        ACC4_(a7, b7, h28, h29, h30, h31);

        float za = bza + fmaf(wia0, x0, fmaf(wia1, x1, (z0 + z1) + (z2 + z3)));
        float zb = bzb + fmaf(wib0, x0, fmaf(wib1, x1, (y0 + y1) + (y2 + y3)));

        // za: lanes 0..31 = i-rows, lanes 32..63 = f-rows
        // zb: lanes 0..31 = g-rows, lanes 32..63 = o-rows
        float zi, zf, zg, zo;
        SPLIT(zi, zf, za);   // zi = lo half replicated, zf = hi half
        SPLIT(zg, zo, zb);   // zg = lo half replicated, zo = hi half

        cst  = fsig(zf) * cst + fsig(zi) * ftanh(zg);
        hval = fsig(zo) * ftanh(cst);

        x0 = nx0; x1 = nx1;
    }

    if (lane < H) hl[dir][lane] = hval;
    __syncthreads();

    if (tid == 0) {
        float v0 = redb[0], v1 = redb[1];
        for (int k = 0; k < H; ++k) {
            v0 += hl[0][k] * redW[k]         + hl[1][k] * redW[H + k];
            v1 += hl[0][k] * redW[2 * H + k] + hl[1][k] * redW[3 * H + k];
        }
        v0 = fmaxf(v0, 0.f);
        v1 = fmaxf(v1, 0.f);
        float m = fmaxf(v0, v1);
        float l = logf(expf(v0 - m) + expf(v1 - m));
        out[0] = v0 - m - l;
        out[1] = v1 - m - l;
    }
}

extern "C" void kernel_launch(void* const* d_in, const int* in_sizes, int n_in,
                              void* d_out, int out_size, void* d_ws, size_t ws_size,
                              hipStream_t stream) {
    const float* x        = (const float*)d_in[0];
    const int*   ei       = (const int*)  d_in[1];
    const int*   batch    = (const int*)  d_in[2];
    const float* gin0_W1  = (const float*)d_in[3];
    const float* gin0_b1  = (const float*)d_in[4];
    const float* gin0_W2  = (const float*)d_in[5];
    const float* gin0_b2  = (const float*)d_in[6];
    const float* bn0_g    = (const float*)d_in[7];
    const float* bn0_b    = (const float*)d_in[8];
    const float* bn0_m    = (const float*)d_in[9];
    const float* bn0_v    = (const float*)d_in[10];
    const float* gin1_W1  = (const float*)d_in[11];
    const float* gin1_b1  = (const float*)d_in[12];
    const float* gin1_W2  = (const float*)d_in[13];
    const float* gin1_b2  = (const float*)d_in[14];
    const float* bn1_g    = (const float*)d_in[15];
    const float* bn1_b    = (const float*)d_in[16];
    const float* bn1_m    = (const float*)d_in[17];
    const float* bn1_v    = (const float*)d_in[18];
    const float* fc1_W    = (const float*)d_in[19];
    const float* fc1_b    = (const float*)d_in[20];
    const float* fc2_W    = (const float*)d_in[21];
    const float* fc2_b    = (const float*)d_in[22];
    const float* Wih_f    = (const float*)d_in[23];
    const float* Whh_f    = (const float*)d_in[24];
    const float* bih_f    = (const float*)d_in[25];
    const float* bhh_f    = (const float*)d_in[26];
    const float* Wih_b    = (const float*)d_in[27];
    const float* Whh_b    = (const float*)d_in[28];
    const float* bih_b    = (const float*)d_in[29];
    const float* bhh_b    = (const float*)d_in[30];
    const float* red_W    = (const float*)d_in[31];
    const float* red_b    = (const float*)d_in[32];

    // workspace layout
    float* ws    = (float*)d_ws;
    float* A     = ws;                          // y buffer   N*H
    float* B     = A + (size_t)N_NODES * H;     // y1 buffer  N*H
    float* gpool = B + (size_t)N_NODES * H;     // G*H
    float* seq   = gpool + (size_t)G * H;       // G*C
    int*   rowptr = (int*)(seq + (size_t)G * C);        // N+1
    int*   cursor = rowptr + (N_NODES + 1);             // N
    int*   bsum   = cursor + N_NODES;                   // 1024
    int*   elist  = bsum + 1024;                        // E

    int nblk_x       = (N_NODES + 7) / 8;          // 12500 (xform0 blocks)
    int nblk_edges   = (N_EDGES + 255) / 256;      // 6250
    int nblk_scan    = (N_NODES + 255) / 256;      // 391
    int nblk_fuse    = (N_NODES + 15) / 16;        // 6250 (16 nodes/block)
    int nblk_scatter = ((N_EDGES + EPB - 1) / EPB) * NPART;  // 782*8 = 6256

    // ---- CSR build + xform0 (fused: independent work, one dispatch)
    k_zero_i<<<nblk_scan, 256, 0, stream>>>(rowptr, N_NODES);
    k_histx<<<nblk_x + nblk_edges, 256, 0, stream>>>(ei, rowptr, x, gin0_W1,
                                                     A, nblk_x);
    k_scan1<<<nblk_scan, 256, 0, stream>>>(rowptr, bsum);
    k_scan3<<<nblk_scan, 256, 0, stream>>>(rowptr, bsum, nblk_scan, cursor, gpool);
    k_scatter<<<nblk_scatter, 256, 0, stream>>>(ei, cursor, elist);

    // ---- layer 0 (fused agg+mlp, writes next-layer y1 into B)
    k_aggmlp0<<<nblk_fuse, 256, 0, stream>>>(rowptr, elist, A,
                                             gin0_b1, gin0_W2, gin0_b2,
                                             bn0_g, bn0_b, bn0_m, bn0_v,
                                             gin1_W1, B);
    // ---- layer 1 (fused agg+mlp+pool)
    k_aggmlp1_pool<<<nblk_fuse, 256, 0, stream>>>(rowptr, elist, B, batch,
                                                  gin1_b1, gin1_W2, gin1_b2,
                                                  bn1_g, bn1_b, bn1_m, bn1_v,
                                                  gpool);
    // ---- dense tail
    k_fc<<<(G + 7) / 8, 256, 0, stream>>>(gpool, fc1_W, fc1_b, fc2_W, fc2_b, seq);
    k_lstm<<<1, 128, 0, stream>>>(seq, Wih_f, Whh_f, bih_f, bhh_f,
                                  Wih_b, Whh_b, bih_b, bhh_b,
                                  red_W, red_b, (float*)d_out);
}

// Round 20
// 416.155 us; speedup vs baseline: 1.1699x; 1.0665x over previous
//
#include <hip/hip_runtime.h>
#include <math.h>

#define N_NODES 100000
#define N_EDGES 1600000
#define F_IN    64
#define H       32
#define C       2
#define G       500
#define BN_EPS  1e-5f

#define NPART        8        // dst partitions == XCD count
#define NODES_PER_P  12500    // 100000 / 8
#define EPB          2048     // edges scanned per block in k_scatter

// ---------------------------------------------------------------- zero utils
__global__ __launch_bounds__(256) void k_zero_i(int* __restrict__ p, int n) {
    int i = blockIdx.x * 256 + threadIdx.x;
    if (i < n) p[i] = 0;
}

// ---- fused: xform0 (blocks [0,nblk_x)) + histogram (rest). Independent work
// sharing one dispatch: hides xform0's serial time under hist's atomics.
__global__ __launch_bounds__(256) void k_histx(
    const int* __restrict__ ei, int* __restrict__ deg,
    const float* __restrict__ x, const float* __restrict__ W1,
    float* __restrict__ y, int nblk_x)
{
    __shared__ float Wt[F_IN * H];   // Wt[k*H+f] = W1[f*F_IN+k]
    __shared__ float xs[8 * F_IN];
    int tid = threadIdx.x;
    if ((int)blockIdx.x >= nblk_x) {
        // ---- histogram part
        int e = ((int)blockIdx.x - nblk_x) * 256 + tid;
        if (e < N_EDGES) atomicAdd(&deg[ei[N_EDGES + e]], 1);
        return;
    }
    // ---- xform0 part: y0 = x @ W1^T (8 nodes/block)
    for (int idx = tid; idx < F_IN * H; idx += 256) {
        int f = idx & (H - 1);
        int k = idx >> 5;
        Wt[k * H + f] = W1[f * F_IN + k];
    }
    int n0 = blockIdx.x * 8;
    for (int idx = tid; idx < 8 * F_IN; idx += 256) {
        int nl = idx >> 6, k = idx & 63;
        int n = n0 + nl;
        xs[idx] = (n < N_NODES) ? x[n * F_IN + k] : 0.f;
    }
    __syncthreads();
    int nl = tid >> 5, f = tid & 31;
    int n = n0 + nl;
    if (n < N_NODES) {
        float acc = 0.f;
#pragma unroll
        for (int k = 0; k < F_IN; ++k) acc += xs[nl * F_IN + k] * Wt[k * H + f];
        y[n * H + f] = acc;
    }
}

// block-level exclusive scan (in place on rowptr), block totals to bsum
__global__ __launch_bounds__(256) void k_scan1(
    int* __restrict__ rowptr, int* __restrict__ bsum)
{
    __shared__ int s[256];
    int i = blockIdx.x * 256 + threadIdx.x;
    int v = (i < N_NODES) ? rowptr[i] : 0;
    s[threadIdx.x] = v;
    __syncthreads();
    for (int off = 1; off < 256; off <<= 1) {
        int t = (threadIdx.x >= off) ? s[threadIdx.x - off] : 0;
        __syncthreads();
        s[threadIdx.x] += t;
        __syncthreads();
    }
    if (i < N_NODES) rowptr[i] = s[threadIdx.x] - v;   // exclusive within block
    if (threadIdx.x == 255) bsum[blockIdx.x] = s[255];
}

// scan2 folded in: each block locally exclusive-scans bsum (nb<=512) in LDS,
// then applies offsets; init cursor; rowptr[N]=E; zero gpool.
__global__ __launch_bounds__(256) void k_scan3(
    int* __restrict__ rowptr, const int* __restrict__ bsum, int nb,
    int* __restrict__ cursor, float* __restrict__ gpool)
{
    __shared__ int sb[512];
    int tid = threadIdx.x;
    for (int j = tid; j < nb; j += 256) sb[j] = bsum[j];
    __syncthreads();
    if (tid == 0) {
        int run = 0;
        for (int j = 0; j < nb; ++j) { int t = sb[j]; sb[j] = run; run += t; }
    }
    __syncthreads();
    int i = blockIdx.x * 256 + tid;
    if (i < N_NODES) {
        int r = rowptr[i] + sb[i >> 8];
        rowptr[i] = r;
        cursor[i] = r;
    }
    if (i == 0) rowptr[N_NODES] = N_EDGES;
    if (i < G * H) gpool[i] = 0.f;
}

// ---- partitioned scatter (verified r17: block b owns dst-partition (b&7),
// scans edge chunk (b>>3); partition's elist range stays resident in one
// XCD's L2 so 4B stores merge into full lines).
__global__ __launch_bounds__(256) void k_scatter(
    const int* __restrict__ ei, int* __restrict__ cursor,
    int* __restrict__ elist)
{
    int p    = blockIdx.x & (NPART - 1);
    int lo   = p * NODES_PER_P;
    int hi   = lo + NODES_PER_P;
    int base = (blockIdx.x >> 3) * EPB;
    for (int i = threadIdx.x; i < EPB; i += 256) {
        int e = base + i;
        if (e < N_EDGES) {
            int d = ei[N_EDGES + e];
            if (d >= lo && d < hi) {
                int pos = atomicAdd(&cursor[d], 1);
                elist[pos] = ei[e];
            }
        }
    }
}

// ======== fused agg + MLP, layer 0 ========
// 32 nodes/block, 8 lanes/node (float4 = 16B/lane). Still one full 128B
// line per neighbor, ~30% fewer wave-instructions/edge than float2 (r18
// showed gather is instruction-issue-bound); divergence tail +~7%.
__global__ __launch_bounds__(256) void k_aggmlp0(
    const int* __restrict__ rowptr, const int* __restrict__ elist,
    const float* __restrict__ y,
    const float* __restrict__ b1, const float* __restrict__ W2,
    const float* __restrict__ b2,
    const float* __restrict__ gamma, const float* __restrict__ beta,
    const float* __restrict__ mean,  const float* __restrict__ var,
    const float* __restrict__ nW,
    float* __restrict__ y_out)
{
    __shared__ float W2t[H * H];     // [k][f]
    __shared__ float nWt[H * H];     // [k][f]
    __shared__ float tb[32][H + 1];  // +1 pad
    __shared__ float hb[32][H + 1];
    int tid = threadIdx.x;
    for (int idx = tid; idx < H * H; idx += 256) {
        int f = idx & 31, k = idx >> 5;
        W2t[k * H + f] = W2[f * H + k];
        nWt[k * H + f] = nW[f * H + k];
    }
    int nl = tid >> 3;           // node-in-block 0..31
    int q  = tid & 7;            // float4 slot
    int n  = blockIdx.x * 32 + nl;
    bool ok = n < N_NODES;

    float4 a = make_float4(0.f, 0.f, 0.f, 0.f), b = a, c = a, d = a;
    if (ok) {
        int j  = rowptr[n];
        int j1 = rowptr[n + 1];
        const float4* y4 = (const float4*)y;
        a = y4[n * 8 + q];                      // self term
        for (; j + 4 <= j1; j += 4) {
            int s0 = elist[j],     s1 = elist[j + 1];
            int s2 = elist[j + 2], s3 = elist[j + 3];
            float4 v0 = y4[s0 * 8 + q];
            float4 v1 = y4[s1 * 8 + q];
            float4 v2 = y4[s2 * 8 + q];
            float4 v3 = y4[s3 * 8 + q];
            a.x += v0.x; a.y += v0.y; a.z += v0.z; a.w += v0.w;
            b.x += v1.x; b.y += v1.y; b.z += v1.z; b.w += v1.w;
            c.x += v2.x; c.y += v2.y; c.z += v2.z; c.w += v2.w;
            d.x += v3.x; d.y += v3.y; d.z += v3.z; d.w += v3.w;
        }
        for (; j < j1; ++j) {
            int s0 = elist[j];
            float4 v0 = y4[s0 * 8 + q];
            a.x += v0.x; a.y += v0.y; a.z += v0.z; a.w += v0.w;
        }
        a.x += b.x + c.x + d.x;
        a.y += b.y + c.y + d.y;
        a.z += b.z + c.z + d.z;
        a.w += b.w + c.w + d.w;
    }
    int f0 = 4 * q;
    tb[nl][f0]     = fmaxf(a.x + b1[f0],     0.f);
    tb[nl][f0 + 1] = fmaxf(a.y + b1[f0 + 1], 0.f);
    tb[nl][f0 + 2] = fmaxf(a.z + b1[f0 + 2], 0.f);
    tb[nl][f0 + 3] = fmaxf(a.w + b1[f0 + 3], 0.f);
    __syncthreads();

    // each thread: outputs f = f0..f0+3 for node nl
    float z0 = b2[f0], z1 = b2[f0 + 1], z2 = b2[f0 + 2], z3 = b2[f0 + 3];
#pragma unroll
    for (int k = 0; k < H; ++k) {
        float tk = tb[nl][k];
        z0 = fmaf(tk, W2t[k * H + f0],     z0);
        z1 = fmaf(tk, W2t[k * H + f0 + 1], z1);
        z2 = fmaf(tk, W2t[k * H + f0 + 2], z2);
        z3 = fmaf(tk, W2t[k * H + f0 + 3], z3);
    }
    z0 = fmaxf(z0, 0.f); z1 = fmaxf(z1, 0.f);
    z2 = fmaxf(z2, 0.f); z3 = fmaxf(z3, 0.f);
    float s0 = gamma[f0]     * rsqrtf(var[f0]     + BN_EPS);
    float s1 = gamma[f0 + 1] * rsqrtf(var[f0 + 1] + BN_EPS);
    float s2 = gamma[f0 + 2] * rsqrtf(var[f0 + 2] + BN_EPS);
    float s3 = gamma[f0 + 3] * rsqrtf(var[f0 + 3] + BN_EPS);
    hb[nl][f0]     = (z0 - mean[f0])     * s0 + beta[f0];
    hb[nl][f0 + 1] = (z1 - mean[f0 + 1]) * s1 + beta[f0 + 1];
    hb[nl][f0 + 2] = (z2 - mean[f0 + 2]) * s2 + beta[f0 + 2];
    hb[nl][f0 + 3] = (z3 - mean[f0 + 3]) * s3 + beta[f0 + 3];
    __syncthreads();

    float yv0 = 0.f, yv1 = 0.f, yv2 = 0.f, yv3 = 0.f;
#pragma unroll
    for (int k = 0; k < H; ++k) {
        float hk = hb[nl][k];
        yv0 = fmaf(hk, nWt[k * H + f0],     yv0);
        yv1 = fmaf(hk, nWt[k * H + f0 + 1], yv1);
        yv2 = fmaf(hk, nWt[k * H + f0 + 2], yv2);
        yv3 = fmaf(hk, nWt[k * H + f0 + 3], yv3);
    }
    if (ok) {
        ((float4*)y_out)[n * 8 + q] = make_float4(yv0, yv1, yv2, yv3);
    }
}

// ======== fused agg + MLP + global_add_pool, layer 1 ========
__global__ __launch_bounds__(256) void k_aggmlp1_pool(
    const int* __restrict__ rowptr, const int* __restrict__ elist,
    const float* __restrict__ y, const int* __restrict__ batch,
    const float* __restrict__ b1, const float* __restrict__ W2,
    const float* __restrict__ b2,
    const float* __restrict__ gamma, const float* __restrict__ beta,
    const float* __restrict__ mean,  const float* __restrict__ var,
    float* __restrict__ gpool)
{
    __shared__ float W2t[H * H];
    __shared__ float tb[32][H + 1];
    __shared__ float hb[32][H + 1];
    __shared__ int   bs[32];
    int tid = threadIdx.x;
    for (int idx = tid; idx < H * H; idx += 256) {
        int f = idx & 31, k = idx >> 5;
        W2t[k * H + f] = W2[f * H + k];
    }
    int nl = tid >> 3;
    int q  = tid & 7;
    int n  = blockIdx.x * 32 + nl;
    bool ok = n < N_NODES;
    if (tid < 32) {
        int nn = blockIdx.x * 32 + tid;
        bs[tid] = (nn < N_NODES) ? batch[nn] : -1;
    }

    float4 a = make_float4(0.f, 0.f, 0.f, 0.f), b = a, c = a, d = a;
    if (ok) {
        int j  = rowptr[n];
        int j1 = rowptr[n + 1];
        const float4* y4 = (const float4*)y;
        a = y4[n * 8 + q];
        for (; j + 4 <= j1; j += 4) {
            int s0 = elist[j],     s1 = elist[j + 1];
            int s2 = elist[j + 2], s3 = elist[j + 3];
            float4 v0 = y4[s0 * 8 + q];
            float4 v1 = y4[s1 * 8 + q];
            float4 v2 = y4[s2 * 8 + q];
            float4 v3 = y4[s3 * 8 + q];
            a.x += v0.x; a.y += v0.y; a.z += v0.z; a.w += v0.w;
            b.x += v1.x; b.y += v1.y; b.z += v1.z; b.w += v1.w;
            c.x += v2.x; c.y += v2.y; c.z += v2.z; c.w += v2.w;
            d.x += v3.x; d.y += v3.y; d.z += v3.z; d.w += v3.w;
        }
        for (; j < j1; ++j) {
            int s0 = elist[j];
            float4 v0 = y4[s0 * 8 + q];
            a.x += v0.x; a.y += v0.y; a.z += v0.z; a.w += v0.w;
        }
        a.x += b.x + c.x + d.x;
        a.y += b.y + c.y + d.y;
        a.z += b.z + c.z + d.z;
        a.w += b.w + c.w + d.w;
    }
    int f0 = 4 * q;
    tb[nl][f0]     = fmaxf(a.x + b1[f0],     0.f);
    tb[nl][f0 + 1] = fmaxf(a.y + b1[f0 + 1], 0.f);
    tb[nl][f0 + 2] = fmaxf(a.z + b1[f0 + 2], 0.f);
    tb[nl][f0 + 3] = fmaxf(a.w + b1[f0 + 3], 0.f);
    __syncthreads();

    float z0 = b2[f0], z1 = b2[f0 + 1], z2 = b2[f0 + 2], z3 = b2[f0 + 3];
#pragma unroll
    for (int k = 0; k < H; ++k) {
        float tk = tb[nl][k];
        z0 = fmaf(tk, W2t[k * H + f0],     z0);
        z1 = fmaf(tk, W2t[k * H + f0 + 1], z1);
        z2 = fmaf(tk, W2t[k * H + f0 + 2], z2);
        z3 = fmaf(tk, W2t[k * H + f0 + 3], z3);
    }
    z0 = fmaxf(z0, 0.f); z1 = fmaxf(z1, 0.f);
    z2 = fmaxf(z2, 0.f); z3 = fmaxf(z3, 0.f);
    float s0 = gamma[f0]     * rsqrtf(var[f0]     + BN_EPS);
    float s1 = gamma[f0 + 1] * rsqrtf(var[f0 + 1] + BN_EPS);
    float s2 = gamma[f0 + 2] * rsqrtf(var[f0 + 2] + BN_EPS);
    float s3 = gamma[f0 + 3] * rsqrtf(var[f0 + 3] + BN_EPS);
    hb[nl][f0]     = (z0 - mean[f0])     * s0 + beta[f0];
    hb[nl][f0 + 1] = (z1 - mean[f0 + 1]) * s1 + beta[f0 + 1];
    hb[nl][f0 + 2] = (z2 - mean[f0 + 2]) * s2 + beta[f0 + 2];
    hb[nl][f0 + 3] = (z3 - mean[f0 + 3]) * s3 + beta[f0 + 3];
    __syncthreads();

    // segment-head combining (batch sorted): one atomic per (segment, f)
    if (ok && (nl == 0 || bs[nl] != bs[nl - 1])) {
        int bid = bs[nl];
        float a0 = hb[nl][f0];
        float a1 = hb[nl][f0 + 1];
        float a2 = hb[nl][f0 + 2];
        float a3 = hb[nl][f0 + 3];
        for (int j = nl + 1; j < 32 && bs[j] == bid; ++j) {
            a0 += hb[j][f0];
            a1 += hb[j][f0 + 1];
            a2 += hb[j][f0 + 2];
            a3 += hb[j][f0 + 3];
        }
        atomicAdd(&gpool[bid * H + f0],     a0);
        atomicAdd(&gpool[bid * H + f0 + 1], a1);
        atomicAdd(&gpool[bid * H + f0 + 2], a2);
        atomicAdd(&gpool[bid * H + f0 + 3], a3);
    }
}

// -------------------- g -> relu(fc1) -> fc2 -> seq[G*C]
__global__ __launch_bounds__(256) void k_fc(
    const float* __restrict__ gpool,
    const float* __restrict__ fc1W, const float* __restrict__ fc1b,
    const float* __restrict__ fc2W, const float* __restrict__ fc2b,
    float* __restrict__ seq)
{
    __shared__ float W1t[H * H];
    __shared__ float gs[8][H];
    __shared__ float tb[8][H];
    int tid = threadIdx.x;
    for (int idx = tid; idx < H * H; idx += 256) {
        int f = idx & 31, k = idx >> 5;
        W1t[k * H + f] = fc1W[f * H + k];
    }
    int n0 = blockIdx.x * 8;
    int nl = tid >> 5, f = tid & 31;
    int g = n0 + nl;
    bool ok = g < G;
    gs[nl][f] = ok ? gpool[g * H + f] : 0.f;
    __syncthreads();
    float z = fc1b[f];
#pragma unroll
    for (int k = 0; k < H; ++k) z += gs[nl][k] * W1t[k * H + f];
    tb[nl][f] = fmaxf(z, 0.f);
    __syncthreads();
    if (ok && f < C) {
        float z2 = fc2b[f];
#pragma unroll
        for (int k = 0; k < H; ++k) z2 += tb[nl][k] * fc2W[f * H + k];
        seq[g * C + f] = z2;
    }
}

// ---------- wave-synchronous bidirectional LSTM ----------
// Gate exchange via v_permlane32_swap_b32 (pure VALU) — verified r15.

#if __has_builtin(__builtin_amdgcn_readlane)
#define RDL(v, k) __int_as_float(__builtin_amdgcn_readlane(__float_as_int(v), (k)))
#else
#define RDL(v, k) __shfl((v), (k), 64)
#endif

#define LOG2E  1.4426950408889634f
#define N2L2E  2.8853900817779268f

#if __has_builtin(__builtin_amdgcn_exp2f) && __has_builtin(__builtin_amdgcn_rcpf)
#define EXP2F(x) __builtin_amdgcn_exp2f(x)
#define RCPF(x)  __builtin_amdgcn_rcpf(x)
#else
#define EXP2F(x) exp2f(x)
#define RCPF(x)  (1.f / (x))
#endif

__device__ __forceinline__ float fsig(float x) {   // 1/(1+e^-x)
    return RCPF(1.f + EXP2F(-LOG2E * x));
}
__device__ __forceinline__ float ftanh(float x) {  // 2/(1+e^-2x) - 1
    return 2.f * RCPF(1.f + EXP2F(-N2L2E * x)) - 1.f;
}

#define PIN4(v) asm("" : "+v"((v).x), "+v"((v).y), "+v"((v).z), "+v"((v).w))

// d_lo = src lanes 0..31 replicated to all; d_hi = src lanes 32..63 replicated.
#define SPLIT(d_lo, d_hi, src)                                            \
    asm("v_mov_b32 %0, %2\n\t"                                            \
        "v_mov_b32 %1, %2\n\t"                                            \
        "v_permlane32_swap_b32 %0, %1"                                    \
        : "=&v"(d_lo), "=&v"(d_hi)                                        \
        : "v"(src));

#define ACC4_(av, bv, hA, hB, hC, hD)                                     \
    z0 = fmaf((av).x, hA, z0); z1 = fmaf((av).y, hB, z1);                 \
    z2 = fmaf((av).z, hC, z2); z3 = fmaf((av).w, hD, z3);                 \
    y0 = fmaf((bv).x, hA, y0); y1 = fmaf((bv).y, hB, y1);                 \
    y2 = fmaf((bv).z, hC, y2); y3 = fmaf((bv).w, hD, y3);

__global__ __launch_bounds__(128, 1) void k_lstm(
    const float* __restrict__ seq,
    const float* __restrict__ Wih_f, const float* __restrict__ Whh_f,
    const float* __restrict__ bih_f, const float* __restrict__ bhh_f,
    const float* __restrict__ Wih_b, const float* __restrict__ Whh_b,
    const float* __restrict__ bih_b, const float* __restrict__ bhh_b,
    const float* __restrict__ redW, const float* __restrict__ redb,
    float* __restrict__ out)
{
    __shared__ float  sq[G * C];
    __shared__ float  hl[2][H];
    __shared__ float4 wl4[2048];   // [dir][ab][k4][lane] float4 = 32 KB
    int tid  = threadIdx.x;
    int dir  = tid >> 6;
    int lane = tid & 63;

    for (int i = tid; i < G * C; i += 128) sq[i] = seq[i];
    for (int i = tid; i < 2048; i += 128) {
        int d  = i >> 10;
        int r  = i & 1023;
        int ab = r >> 9;
        int k4 = (r >> 6) & 7;
        int l  = r & 63;
        const float4* src4 = (const float4*)(d ? Whh_b : Whh_f);
        wl4[i] = src4[(ab * 64 + l) * 8 + k4];
    }
    __syncthreads();

    const float* Wih = dir ? Wih_b : Wih_f;
    const float* bih = dir ? bih_b : bih_f;
    const float* bhh = dir ? bhh_b : bhh_f;

    int ra = lane;
    int rb = lane + 64;

    const float4* wA = &wl4[dir * 1024];
    const float4* wB = &wl4[dir * 1024 + 512];

    float4 a0 = wA[0 * 64 + lane], a1 = wA[1 * 64 + lane];
    float4 a2 = wA[2 * 64 + lane], a3 = wA[3 * 64 + lane];
    float4 a4 = wA[4 * 64 + lane], a5 = wA[5 * 64 + lane];
    float4 a6 = wA[6 * 64 + lane], a7 = wA[7 * 64 + lane];
    float4 b0 = wB[0 * 64 + lane], b1 = wB[1 * 64 + lane];
    float4 b2 = wB[2 * 64 + lane], b3 = wB[3 * 64 + lane];
    float4 b4 = wB[4 * 64 + lane], b5 = wB[5 * 64 + lane];
    float4 b6 = wB[6 * 64 + lane], b7 = wB[7 * 64 + lane];
    PIN4(a0); PIN4(a1); PIN4(a2); PIN4(a3);
    PIN4(a4); PIN4(a5); PIN4(a6); PIN4(a7);
    PIN4(b0); PIN4(b1); PIN4(b2); PIN4(b3);
    PIN4(b4); PIN4(b5); PIN4(b6); PIN4(b7);

    float wia0 = Wih[ra * C], wia1 = Wih[ra * C + 1];
    float wib0 = Wih[rb * C], wib1 = Wih[rb * C + 1];
    float bza  = bih[ra] + bhh[ra];
    float bzb  = bih[rb] + bhh[rb];

    float hval = 0.f;
    float cst  = 0.f;

    int tt0 = dir ? (G - 1) : 0;
    float x0 = sq[tt0 * C];
    float x1 = sq[tt0 * C + 1];

#pragma unroll 2
    for (int t = 0; t < G; ++t) {
        int tn = (t + 1 < G) ? (dir ? (G - 2 - t) : (t + 1)) : 0;
        float nx0 = sq[tn * C];
        float nx1 = sq[tn * C + 1];

        float h0  = RDL(hval, 0),  h1  = RDL(hval, 1);
        float h2  = RDL(hval, 2),  h3  = RDL(hval, 3);
        float h4  = RDL(hval, 4),  h5  = RDL(hval, 5);
        float h6  = RDL(hval, 6),  h7  = RDL(hval, 7);
        float h8  = RDL(hval, 8),  h9  = RDL(hval, 9);
        float h10 = RDL(hval, 10), h11 = RDL(hval, 11);
        float h12 = RDL(hval, 12), h13 = RDL(hval, 13);
        float h14 = RDL(hval, 14), h15 = RDL(hval, 15);
        float h16 = RDL(hval, 16), h17 = RDL(hval, 17);
        float h18 = RDL(hval, 18), h19 = RDL(hval, 19);
        float h20 = RDL(hval, 20), h21 = RDL(hval, 21);
        float h22 = RDL(hval, 22), h23 = RDL(hval, 23);
        float h24 = RDL(hval, 24), h25 = RDL(hval, 25);
        float h26 = RDL(hval, 26), h27 = RDL(hval, 27);
        float h28 = RDL(hval, 28), h29 = RDL(hval, 29);
        float h30 = RDL(hval, 30), h31 = RDL(hval, 31);

        float z0 = 0.f, z1 = 0.f, z2 = 0.f, z3 = 0.f;
        float y0 = 0.f, y1 = 0.f, y2 = 0.f, y3 = 0.f;
        ACC4_(a0, b0, h0,  h1,  h2,  h3);
        ACC4_(a1, b1, h4,  h5,  h6,  h7);
        ACC4_(a2, b2, h8,  h9,  h10, h11);
        ACC4_(a3, b3, h12, h13, h14, h15);
        ACC4_(a4, b4, h16, h17, h18, h19);
        ACC4_(a5, b5, h20, h21, h22, h23);
        ACC4_(a6, b6, h24, h25, h26, h27);
        ACC4_(a7, b7, h28, h29, h30, h31);

        float za = bza + fmaf(wia0, x0, fmaf(wia1, x1, (z0 + z1) + (z2 + z3)));
        float zb = bzb + fmaf(wib0, x0, fmaf(wib1, x1, (y0 + y1) + (y2 + y3)));

        // za: lanes 0..31 = i-rows, lanes 32..63 = f-rows
        // zb: lanes 0..31 = g-rows, lanes 32..63 = o-rows
        float zi, zf, zg, zo;
        SPLIT(zi, zf, za);   // zi = lo half replicated, zf = hi half
        SPLIT(zg, zo, zb);   // zg = lo half replicated, zo = hi half

        cst  = fsig(zf) * cst + fsig(zi) * ftanh(zg);
        hval = fsig(zo) * ftanh(cst);

        x0 = nx0; x1 = nx1;
    }

    if (lane < H) hl[dir][lane] = hval;
    __syncthreads();

    if (tid == 0) {
        float v0 = redb[0], v1 = redb[1];
        for (int k = 0; k < H; ++k) {
            v0 += hl[0][k] * redW[k]         + hl[1][k] * redW[H + k];
            v1 += hl[0][k] * redW[2 * H + k] + hl[1][k] * redW[3 * H + k];
        }
        v0 = fmaxf(v0, 0.f);
        v1 = fmaxf(v1, 0.f);
        float m = fmaxf(v0, v1);
        float l = logf(expf(v0 - m) + expf(v1 - m));
        out[0] = v0 - m - l;
        out[1] = v1 - m - l;
    }
}

extern "C" void kernel_launch(void* const* d_in, const int* in_sizes, int n_in,
                              void* d_out, int out_size, void* d_ws, size_t ws_size,
                              hipStream_t stream) {
    const float* x        = (const float*)d_in[0];
    const int*   ei       = (const int*)  d_in[1];
    const int*   batch    = (const int*)  d_in[2];
    const float* gin0_W1  = (const float*)d_in[3];
    const float* gin0_b1  = (const float*)d_in[4];
    const float* gin0_W2  = (const float*)d_in[5];
    const float* gin0_b2  = (const float*)d_in[6];
    const float* bn0_g    = (const float*)d_in[7];
    const float* bn0_b    = (const float*)d_in[8];
    const float* bn0_m    = (const float*)d_in[9];
    const float* bn0_v    = (const float*)d_in[10];
    const float* gin1_W1  = (const float*)d_in[11];
    const float* gin1_b1  = (const float*)d_in[12];
    const float* gin1_W2  = (const float*)d_in[13];
    const float* gin1_b2  = (const float*)d_in[14];
    const float* bn1_g    = (const float*)d_in[15];
    const float* bn1_b    = (const float*)d_in[16];
    const float* bn1_m    = (const float*)d_in[17];
    const float* bn1_v    = (const float*)d_in[18];
    const float* fc1_W    = (const float*)d_in[19];
    const float* fc1_b    = (const float*)d_in[20];
    const float* fc2_W    = (const float*)d_in[21];
    const float* fc2_b    = (const float*)d_in[22];
    const float* Wih_f    = (const float*)d_in[23];
    const float* Whh_f    = (const float*)d_in[24];
    const float* bih_f    = (const float*)d_in[25];
    const float* bhh_f    = (const float*)d_in[26];
    const float* Wih_b    = (const float*)d_in[27];
    const float* Whh_b    = (const float*)d_in[28];
    const float* bih_b    = (const float*)d_in[29];
    const float* bhh_b    = (const float*)d_in[30];
    const float* red_W    = (const float*)d_in[31];
    const float* red_b    = (const float*)d_in[32];

    // workspace layout
    float* ws    = (float*)d_ws;
    float* A     = ws;                          // y buffer   N*H
    float* B     = A + (size_t)N_NODES * H;     // y1 buffer  N*H
    float* gpool = B + (size_t)N_NODES * H;     // G*H
    float* seq   = gpool + (size_t)G * H;       // G*C
    int*   rowptr = (int*)(seq + (size_t)G * C);        // N+1
    int*   cursor = rowptr + (N_NODES + 1);             // N
    int*   bsum   = cursor + N_NODES;                   // 1024
    int*   elist  = bsum + 1024;                        // E

    int nblk_x       = (N_NODES + 7) / 8;          // 12500 (xform0 blocks)
    int nblk_edges   = (N_EDGES + 255) / 256;      // 6250
    int nblk_scan    = (N_NODES + 255) / 256;      // 391
    int nblk_fuse    = (N_NODES + 31) / 32;        // 3125 (32 nodes/block)
    int nblk_scatter = ((N_EDGES + EPB - 1) / EPB) * NPART;  // 782*8 = 6256

    // ---- CSR build + xform0 (fused: independent work, one dispatch)
    k_zero_i<<<nblk_scan, 256, 0, stream>>>(rowptr, N_NODES);
    k_histx<<<nblk_x + nblk_edges, 256, 0, stream>>>(ei, rowptr, x, gin0_W1,
                                                     A, nblk_x);
    k_scan1<<<nblk_scan, 256, 0, stream>>>(rowptr, bsum);
    k_scan3<<<nblk_scan, 256, 0, stream>>>(rowptr, bsum, nblk_scan, cursor, gpool);
    k_scatter<<<nblk_scatter, 256, 0, stream>>>(ei, cursor, elist);

    // ---- layer 0 (fused agg+mlp, writes next-layer y1 into B)
    k_aggmlp0<<<nblk_fuse, 256, 0, stream>>>(rowptr, elist, A,
                                             gin0_b1, gin0_W2, gin0_b2,
                                             bn0_g, bn0_b, bn0_m, bn0_v,
                                             gin1_W1, B);
    // ---- layer 1 (fused agg+mlp+pool)
    k_aggmlp1_pool<<<nblk_fuse, 256, 0, stream>>>(rowptr, elist, B, batch,
                                                  gin1_b1, gin1_W2, gin1_b2,
                                                  bn1_g, bn1_b, bn1_m, bn1_v,
                                                  gpool);
    // ---- dense tail
    k_fc<<<(G + 7) / 8, 256, 0, stream>>>(gpool, fc1_W, fc1_b, fc2_W, fc2_b, seq);
    k_lstm<<<1, 128, 0, stream>>>(seq, Wih_f, Whh_f, bih_f, bhh_f,
                                  Wih_b, Whh_b, bih_b, bhh_b,
                                  red_W, red_b, (float*)d_out);
}